// Round 13
// baseline (679.601 us; speedup 1.0000x reference)
//
#include <hip/hip_runtime.h>

#define NC 300000
#define NP 150000
#define NG 2000
#define NB 500
#define SCAN_B 1024
#define BK_SHIFT 11
#define BK_KEYS 2048     // keys per bucket
#define CBASE (NC + 1)   // first product key
#define RTOT (CBASE + 5 * NP + 1)   // 1,050,002 keys (+ tail)
#define NBKT 513         // cdiv(RTOT, BK_KEYS)
#define CH 8192          // edges per chunk (bcount/msplit)
#define ROWS (NP + NC)   // 450,000 unified rows (product first)
#define RCH 4096         // rows per block in row-sort kernels

typedef unsigned int u32;
typedef float  f32x4 __attribute__((ext_vector_type(4)));
typedef unsigned int u32x4 __attribute__((ext_vector_type(4)));

static inline unsigned cdiv(long long a, long long b) { return (unsigned)((a + b - 1) / b); }

// ---------- bf16 helpers ----------
__device__ __forceinline__ float b2f(u32 h) {
    union { u32 u; float f; } c; c.u = h << 16; return c.f;
}
__device__ __forceinline__ u32 f2b(float f) {
    union { float f; u32 u; } c; c.f = f;
    return (c.u + 0x7FFFu + ((c.u >> 16) & 1u)) >> 16;   // RNE
}
__device__ __forceinline__ void unpack8(uint4 v, float* o) {
    o[0] = b2f(v.x & 0xFFFFu); o[1] = b2f(v.x >> 16);
    o[2] = b2f(v.y & 0xFFFFu); o[3] = b2f(v.y >> 16);
    o[4] = b2f(v.z & 0xFFFFu); o[5] = b2f(v.z >> 16);
    o[6] = b2f(v.w & 0xFFFFu); o[7] = b2f(v.w >> 16);
}
__device__ __forceinline__ void unpack8v(u32x4 v, float* o) {
    o[0] = b2f(v.x & 0xFFFFu); o[1] = b2f(v.x >> 16);
    o[2] = b2f(v.y & 0xFFFFu); o[3] = b2f(v.y >> 16);
    o[4] = b2f(v.z & 0xFFFFu); o[5] = b2f(v.z >> 16);
    o[6] = b2f(v.w & 0xFFFFu); o[7] = b2f(v.w >> 16);
}
__device__ __forceinline__ uint4 pack8(const float* a) {
    uint4 v;
    v.x = f2b(a[0]) | (f2b(a[1]) << 16);
    v.y = f2b(a[2]) | (f2b(a[3]) << 16);
    v.z = f2b(a[4]) | (f2b(a[5]) << 16);
    v.w = f2b(a[6]) | (f2b(a[7]) << 16);
    return v;
}

// ---------- fused f32->bf16 convert of all 4 tables (+ f32 copy for g/b outputs) ----------
__global__ void convert_all(const float* __restrict__ cw, const float* __restrict__ pw,
                            const float* __restrict__ gw, const float* __restrict__ bw,
                            uint4* __restrict__ c16, uint4* __restrict__ p16,
                            uint4* __restrict__ g16, uint4* __restrict__ b16,
                            float* __restrict__ outg, float* __restrict__ outb) {
    const int C8 = NC * 8, P8 = NP * 8, G8 = NG * 8, B8 = NB * 8;
    int i = blockIdx.x * blockDim.x + threadIdx.x;
    const float* in; uint4* out16; float* cpy = nullptr; int j;
    if (i < C8)                         { in = cw; out16 = c16; j = i; }
    else if ((j = i - C8) < P8)         { in = pw; out16 = p16; }
    else if ((j = i - C8 - P8) < G8)    { in = gw; out16 = g16; cpy = outg; }
    else if ((j = i - C8 - P8 - G8) < B8){ in = bw; out16 = b16; cpy = outb; }
    else return;
    const float4* p = (const float4*)(in + (size_t)j * 8);
    float4 a = p[0], b = p[1];
    float t[8] = { a.x, a.y, a.z, a.w, b.x, b.y, b.z, b.w };
    out16[j] = pack8(t);
    if (cpy) { float4* q = (float4*)(cpy + (size_t)j * 8); q[0] = a; q[1] = b; }
}

// ---------- fused CSR build over all 6 edge sets (row-major product keys) ----------
struct Edges6 {
    const int* src[6];
    const int* dst[6];
    int cum[7];      // cumulative edge-count offsets (cum[6] = total)
};

__device__ __forceinline__ int edge_key(int k, int src) {
    return (k == 0) ? src : CBASE + src * 5 + (k - 1);
}

// ---------- stage A: bucket-granularity counts via LDS histogram ----------
__global__ void bcount(Edges6 e, int* __restrict__ gcount, int total) {
    __shared__ int hist[NBKT];
    int t = threadIdx.x;
    int j0 = blockIdx.x * CH;
    for (int b = t; b < NBKT; b += blockDim.x) hist[b] = 0;
    __syncthreads();
    #pragma unroll 4
    for (int q = 0; q < CH / 256; ++q) {
        int j = j0 + q * 256 + t;
        if (j < total) {
            int k = 0;
            #pragma unroll
            for (int qq = 1; qq < 6; ++qq) k += (j >= e.cum[qq]);
            int key = edge_key(k, __builtin_nontemporal_load(e.src[k] + (j - e.cum[k])));
            atomicAdd(&hist[key >> BK_SHIFT], 1);
        }
    }
    __syncthreads();
    for (int b = t; b < NBKT; b += blockDim.x) {
        int c = hist[b];
        if (c > 0) atomicAdd(gcount + b, c);
    }
}

// ---------- stage B: one-block scan of bucket counts -> gbase, gcur ----------
__global__ void bscan(const int* __restrict__ gcount, int* __restrict__ gbase,
                      int* __restrict__ gcur, int nb) {
    __shared__ int sm[SCAN_B];
    int t = threadIdx.x;
    int v = (t < nb) ? gcount[t] : 0;
    sm[t] = v; __syncthreads();
    for (int off = 1; off < SCAN_B; off <<= 1) {
        int add = (t >= off) ? sm[t - off] : 0;
        __syncthreads();
        sm[t] += add; __syncthreads();
    }
    int excl = sm[t] - v;
    if (t < nb) { gbase[t] = excl; gcur[t] = excl; }
    if (t == nb - 1) gbase[nb] = sm[t];
}

// ---------- stage C: 3-phase multisplit into buckets, dense stage writes ----------
// stage word = (key & 2047) << 19 | dst   (dst < 2^19)
__global__ void msplit(Edges6 e, int* __restrict__ gcur, u32* __restrict__ stage, int total) {
    __shared__ int hist[NBKT];
    __shared__ int bse[NBKT];
    int t = threadIdx.x;
    int j0 = blockIdx.x * CH;
    for (int b = t; b < NBKT; b += blockDim.x) hist[b] = 0;
    __syncthreads();
    #pragma unroll 4
    for (int q = 0; q < CH / 256; ++q) {
        int j = j0 + q * 256 + t;
        if (j < total) {
            int k = 0;
            #pragma unroll
            for (int qq = 1; qq < 6; ++qq) k += (j >= e.cum[qq]);
            int key = edge_key(k, __builtin_nontemporal_load(e.src[k] + (j - e.cum[k])));
            atomicAdd(&hist[key >> BK_SHIFT], 1);
        }
    }
    __syncthreads();
    for (int b = t; b < NBKT; b += blockDim.x) {
        int c = hist[b];
        bse[b] = (c > 0) ? atomicAdd(gcur + b, c) : 0;
        hist[b] = 0;
    }
    __syncthreads();
    #pragma unroll 4
    for (int q = 0; q < CH / 256; ++q) {
        int j = j0 + q * 256 + t;
        if (j < total) {
            int k = 0;
            #pragma unroll
            for (int qq = 1; qq < 6; ++qq) k += (j >= e.cum[qq]);
            int jj = j - e.cum[k];
            int key = edge_key(k, __builtin_nontemporal_load(e.src[k] + jj));
            int d = __builtin_nontemporal_load(e.dst[k] + jj);
            int b = key >> BK_SHIFT;
            int off = atomicAdd(&hist[b], 1);
            stage[bse[b] + off] = ((u32)(key & (BK_KEYS - 1)) << 19) | (u32)d;
        }
    }
}

// ---------- stage D: per-bucket LDS histogram+scan -> rowptr slice + place pm ----------
__global__ void sortb(const int* __restrict__ gbase, const u32* __restrict__ stage,
                      int* __restrict__ pm, int* __restrict__ rp, int rtot) {
    __shared__ int cur[BK_KEYS];
    __shared__ int part[512];
    int b = blockIdx.x, t = threadIdx.x;
    int k0 = b << BK_SHIFT;
    int base = gbase[b], end = gbase[b + 1];
    for (int q = t; q < BK_KEYS; q += 512) cur[q] = 0;
    __syncthreads();
    for (int i = base + t; i < end; i += 512)
        atomicAdd(&cur[stage[i] >> 19], 1);
    __syncthreads();
    int a0 = cur[4 * t], a1 = cur[4 * t + 1], a2 = cur[4 * t + 2], a3 = cur[4 * t + 3];
    int s = a0 + a1 + a2 + a3;
    part[t] = s; __syncthreads();
    for (int off = 1; off < 512; off <<= 1) {
        int add = (t >= off) ? part[t - off] : 0;
        __syncthreads();
        part[t] += add; __syncthreads();
    }
    int c0 = base + part[t] - s;
    int c1 = c0 + a0, c2 = c1 + a1, c3 = c2 + a2;
    cur[4 * t] = c0; cur[4 * t + 1] = c1; cur[4 * t + 2] = c2; cur[4 * t + 3] = c3;
    int ki = k0 + 4 * t;
    if (ki + 3 < rtot) {
        *(int4*)(rp + ki) = make_int4(c0, c1, c2, c3);
    } else {
        if (ki     < rtot) rp[ki]     = c0;
        if (ki + 1 < rtot) rp[ki + 1] = c1;
        if (ki + 2 < rtot) rp[ki + 2] = c2;
        if (ki + 3 < rtot) rp[ki + 3] = c3;
    }
    __syncthreads();
    for (int i = base + t; i < end; i += 512) {
        u32 w = stage[i];
        int off = atomicAdd(&cur[w >> 19], 1);
        pm[off] = (int)(w & 0x7FFFFu);
    }
}

// ---------- row workload bin: product rows 0..127, customer rows 128..255 ----------
__device__ __forceinline__ int row_bin(const int* __restrict__ rp, int gid) {
    if (gid < NP) {
        int o = CBASE + gid * 5;
        int td = rp[o + 5] - rp[o];           // merged run length
        return td < 127 ? td : 127;
    } else {
        int r = gid - NP;
        int d = rp[r + 1] - rp[r];
        return 128 + (d < 127 ? d : 127);
    }
}

__global__ void rowhist(const int* __restrict__ rp, int* __restrict__ gbinc, int rows) {
    __shared__ int hist[256];
    int t = threadIdx.x;
    hist[t] = 0;
    __syncthreads();
    int j0 = blockIdx.x * RCH;
    for (int q = 0; q < RCH / 256; ++q) {
        int j = j0 + q * 256 + t;
        if (j < rows) atomicAdd(&hist[row_bin(rp, j)], 1);
    }
    __syncthreads();
    int c = hist[t];
    if (c > 0) atomicAdd(gbinc + t, c);
}

__global__ void rowscan(const int* __restrict__ gbinc, int* __restrict__ gcur256) {
    __shared__ int sm[256];
    int t = threadIdx.x;
    int v = gbinc[t];
    sm[t] = v; __syncthreads();
    for (int off = 1; off < 256; off <<= 1) {
        int add = (t >= off) ? sm[t - off] : 0;
        __syncthreads();
        sm[t] += add; __syncthreads();
    }
    gcur256[t] = sm[t] - v;
}

__global__ void rowplace(const int* __restrict__ rp, int* __restrict__ gcur256,
                         int* __restrict__ perm, int rows) {
    __shared__ int hist[256];
    __shared__ int bse[256];
    int t = threadIdx.x;
    hist[t] = 0;
    __syncthreads();
    int j0 = blockIdx.x * RCH;
    for (int q = 0; q < RCH / 256; ++q) {
        int j = j0 + q * 256 + t;
        if (j < rows) atomicAdd(&hist[row_bin(rp, j)], 1);
    }
    __syncthreads();
    int c = hist[t];
    bse[t] = (c > 0) ? atomicAdd(gcur256 + t, c) : 0;
    hist[t] = 0;
    __syncthreads();
    for (int q = 0; q < RCH / 256; ++q) {
        int j = j0 + q * 256 + t;
        if (j < rows) {
            int b = row_bin(rp, j);
            int off = atomicAdd(&hist[b], 1);
            perm[bse[b] + off] = j;
        }
    }
}

// materialize permuted segment bounds: product = 6 contiguous rp values
__global__ void permrp(const int* __restrict__ rp, const int* __restrict__ perm,
                       int4* __restrict__ pA, int2* __restrict__ pC,
                       int2* __restrict__ cinfo, int rows) {
    int j = blockIdx.x * blockDim.x + threadIdx.x;
    if (j >= rows) return;
    int pg = perm[j];
    if (pg < NP) {
        const int* r0 = rp + CBASE + pg * 5;
        pA[j] = make_int4(r0[0], r0[1], r0[2], r0[3]);
        pC[j] = make_int2(r0[4], r0[5]);
    } else {
        int r = pg - NP;
        cinfo[j - NP] = make_int2(rp[r], rp[r + 1]);
    }
}

// ---------- customer-side mean-agg (single segment) ----------
__device__ __forceinline__ void acc8(uint4 v, float* sum) {
    float t[8]; unpack8(v, t);
    #pragma unroll
    for (int k = 0; k < 8; ++k) sum[k] += t[k];
}
__device__ __forceinline__ void agg8se(int s, int e, const int* __restrict__ pm,
                                       const uint4* __restrict__ tgt,
                                       int lane, float* acc) {
    float sum[8] = {0, 0, 0, 0, 0, 0, 0, 0};
    int i = s;
    for (; i + 4 <= e; i += 4) {
        int d0 = pm[i], d1 = pm[i + 1], d2 = pm[i + 2], d3 = pm[i + 3];
        uint4 v0 = tgt[(size_t)d0 * 8 + lane];
        uint4 v1 = tgt[(size_t)d1 * 8 + lane];
        uint4 v2 = tgt[(size_t)d2 * 8 + lane];
        uint4 v3 = tgt[(size_t)d3 * 8 + lane];
        acc8(v0, sum); acc8(v1, sum); acc8(v2, sum); acc8(v3, sum);
    }
    for (; i < e; ++i) {
        uint4 v = tgt[(size_t)pm[i] * 8 + lane];
        acc8(v, sum);
    }
    int deg = e - s;
    float sc = 1.0f / (float)(deg > 1 ? deg : 1);
    #pragma unroll
    for (int k = 0; k < 8; ++k) acc[k] += sum[k] * sc;
}

// per-edge table/scale select for the merged product run
__device__ __forceinline__ const uint4* tblsel(int i, int b1, int b3, int b4,
                                               const uint4* c16, const uint4* p16,
                                               const uint4* g16, const uint4* b16) {
    const uint4* t = c16;
    if (i >= b1) t = p16;     // sim & cop both read p16
    if (i >= b3) t = g16;
    if (i >= b4) t = b16;
    return t;
}
__device__ __forceinline__ float sclsel(int i, int b1, int b2, int b3, int b4,
                                        float s0, float s1, float s2, float s3, float s4) {
    float s = s0;
    if (i >= b1) s = s1;
    if (i >= b2) s = s2;
    if (i >= b3) s = s3;
    if (i >= b4) s = s4;
    return s;
}
__device__ __forceinline__ void accw(uint4 v, float s, float* acc) {
    float t[8]; unpack8(v, t);
    #pragma unroll
    for (int k = 0; k < 8; ++k) acc[k] += t[k] * s;
}

// ---------- fused layer (degree-balanced rows, merged product runs) ----------
// modes 0/1: write next-snapshot only. mode 2: out = 0.25*(s0+s1+s2+acc).
__global__ void layer_kernel(
    const int* __restrict__ perm,
    const int4* __restrict__ pA, const int2* __restrict__ pC,
    const int2* __restrict__ cinfo,
    const int* __restrict__ pm,
    const uint4* __restrict__ c16, const uint4* __restrict__ p16,
    const uint4* __restrict__ g16, const uint4* __restrict__ b16,
    uint4* __restrict__ c16n, uint4* __restrict__ p16n,
    const float* __restrict__ cw, const float* __restrict__ pw,
    const uint4* __restrict__ s1c, const uint4* __restrict__ s1p,
    float* __restrict__ outc, float* __restrict__ outp,
    int mode)
{
    int t = blockIdx.x * blockDim.x + threadIdx.x;
    int gid = t >> 3;
    int lane = t & 7;
    float acc[8];
    if (gid < NP) {
        int row = perm[gid];                      // original product row
        size_t idx = (size_t)row * 8 + lane;
        int4 ia = pA[gid];
        int2 ic = pC[gid];
        int b0 = ia.x, b1 = ia.y, b2 = ia.z, b3 = ia.w, b4 = ic.x, b5 = ic.y;
        int d0g = b1 - b0, d1g = b2 - b1, d2g = b3 - b2, d3g = b4 - b3, d4g = b5 - b4;
        float s0 = 1.0f / (float)(d0g > 1 ? d0g : 1);
        float s1 = 0.5f / (float)(d1g > 1 ? d1g : 1);
        float s2 = 0.3f / (float)(d2g > 1 ? d2g : 1);
        float s3 = 0.2f / (float)(d3g > 1 ? d3g : 1);
        float s4 = 0.2f / (float)(d4g > 1 ? d4g : 1);
        float base[8]; unpack8(p16[idx], base);
        #pragma unroll
        for (int k = 0; k < 8; ++k) acc[k] = base[k];
        int i = b0;
        for (; i + 4 <= b5; i += 4) {
            int e0 = pm[i], e1 = pm[i + 1], e2 = pm[i + 2], e3 = pm[i + 3];
            const uint4* t0 = tblsel(i,     b1, b3, b4, c16, p16, g16, b16);
            const uint4* t1 = tblsel(i + 1, b1, b3, b4, c16, p16, g16, b16);
            const uint4* t2 = tblsel(i + 2, b1, b3, b4, c16, p16, g16, b16);
            const uint4* t3 = tblsel(i + 3, b1, b3, b4, c16, p16, g16, b16);
            float w0 = sclsel(i,     b1, b2, b3, b4, s0, s1, s2, s3, s4);
            float w1 = sclsel(i + 1, b1, b2, b3, b4, s0, s1, s2, s3, s4);
            float w2 = sclsel(i + 2, b1, b2, b3, b4, s0, s1, s2, s3, s4);
            float w3 = sclsel(i + 3, b1, b2, b3, b4, s0, s1, s2, s3, s4);
            uint4 v0 = t0[(size_t)e0 * 8 + lane];
            uint4 v1 = t1[(size_t)e1 * 8 + lane];
            uint4 v2 = t2[(size_t)e2 * 8 + lane];
            uint4 v3 = t3[(size_t)e3 * 8 + lane];
            accw(v0, w0, acc); accw(v1, w1, acc); accw(v2, w2, acc); accw(v3, w3, acc);
        }
        for (; i < b5; ++i) {
            int e0 = pm[i];
            const uint4* t0 = tblsel(i, b1, b3, b4, c16, p16, g16, b16);
            float w0 = sclsel(i, b1, b2, b3, b4, s0, s1, s2, s3, s4);
            uint4 v0 = t0[(size_t)e0 * 8 + lane];
            accw(v0, w0, acc);
        }
        if (mode != 2) {
            p16n[idx] = pack8(acc);
        } else {
            const f32x4* s0p = (const f32x4*)(pw + (size_t)row * 64 + lane * 8);
            f32x4 a0 = __builtin_nontemporal_load(s0p);
            f32x4 a1 = __builtin_nontemporal_load(s0p + 1);
            u32x4 s1v = __builtin_nontemporal_load((const u32x4*)&s1p[idx]);
            float sv[8]; unpack8v(s1v, sv);
            f32x4 o0, o1;
            o0.x = 0.25f * (a0.x + sv[0] + base[0] + acc[0]);
            o0.y = 0.25f * (a0.y + sv[1] + base[1] + acc[1]);
            o0.z = 0.25f * (a0.z + sv[2] + base[2] + acc[2]);
            o0.w = 0.25f * (a0.w + sv[3] + base[3] + acc[3]);
            o1.x = 0.25f * (a1.x + sv[4] + base[4] + acc[4]);
            o1.y = 0.25f * (a1.y + sv[5] + base[5] + acc[5]);
            o1.z = 0.25f * (a1.z + sv[6] + base[6] + acc[6]);
            o1.w = 0.25f * (a1.w + sv[7] + base[7] + acc[7]);
            f32x4* o = (f32x4*)(outp + (size_t)row * 64 + lane * 8);
            __builtin_nontemporal_store(o0, o);
            __builtin_nontemporal_store(o1, o + 1);
        }
    } else if (gid < ROWS) {
        int row = perm[gid] - NP;                 // original customer row
        size_t idx = (size_t)row * 8 + lane;
        int2 se = cinfo[gid - NP];
        #pragma unroll
        for (int k = 0; k < 8; ++k) acc[k] = 0.f;
        agg8se(se.x, se.y, pm, p16, lane, acc);
        if (mode != 2) {
            c16n[idx] = pack8(acc);
        } else {
            float base[8]; unpack8(c16[idx], base);                       // s2
            const f32x4* s0c = (const f32x4*)(cw + (size_t)row * 64 + lane * 8);
            f32x4 a0 = __builtin_nontemporal_load(s0c);
            f32x4 a1 = __builtin_nontemporal_load(s0c + 1);
            u32x4 s1v = __builtin_nontemporal_load((const u32x4*)&s1c[idx]);
            float sv[8]; unpack8v(s1v, sv);                               // s1
            f32x4 o0, o1;
            o0.x = 0.25f * (a0.x + sv[0] + base[0] + acc[0]);
            o0.y = 0.25f * (a0.y + sv[1] + base[1] + acc[1]);
            o0.z = 0.25f * (a0.z + sv[2] + base[2] + acc[2]);
            o0.w = 0.25f * (a0.w + sv[3] + base[3] + acc[3]);
            o1.x = 0.25f * (a1.x + sv[4] + base[4] + acc[4]);
            o1.y = 0.25f * (a1.y + sv[5] + base[5] + acc[5]);
            o1.z = 0.25f * (a1.z + sv[6] + base[6] + acc[6]);
            o1.w = 0.25f * (a1.w + sv[7] + base[7] + acc[7]);
            f32x4* o = (f32x4*)(outc + (size_t)row * 64 + lane * 8);
            __builtin_nontemporal_store(o0, o);
            __builtin_nontemporal_store(o1, o + 1);
        }
    }
}

extern "C" void kernel_launch(void* const* d_in, const int* in_sizes, int n_in,
                              void* d_out, int out_size, void* d_ws, size_t ws_size,
                              hipStream_t stream) {
    const float* cust_w  = (const float*)d_in[0];
    const float* prod_w  = (const float*)d_in[1];
    const float* group_w = (const float*)d_in[2];
    const float* brand_w = (const float*)d_in[3];

    const int n_purch = in_sizes[4];
    const int n_pby   = in_sizes[6];
    const int n_sim   = in_sizes[8];
    const int n_cop   = in_sizes[10];
    const int n_bel   = in_sizes[12];
    const int n_comp  = in_sizes[14];
    const int n_edges[6] = { n_purch, n_pby, n_sim, n_cop, n_bel, n_comp };

    const size_t CSZ = (size_t)NC * 64;
    const size_t PSZ = (size_t)NP * 64;

    // ---- workspace layout ----
    char* base = (char*)d_ws;
    uint4* c16A = (uint4*)base;                 base += (size_t)NC * 128;
    uint4* c16B = (uint4*)base;                 base += (size_t)NC * 128;
    uint4* p16A = (uint4*)base;                 base += (size_t)NP * 128;
    uint4* p16B = (uint4*)base;                 base += (size_t)NP * 128;
    uint4* g16  = (uint4*)base;                 base += (size_t)NG * 128;
    uint4* b16  = (uint4*)base;                 base += (size_t)NB * 128;

    int* rp_all = (int*)base;                   base += (size_t)RTOT * 4;
    long long tot_edges = 0;
    for (int k = 0; k < 6; ++k) tot_edges += n_edges[k];
    int* pm_all = (int*)base;                   base += tot_edges * 4;
    u32* stage  = (u32*)base;                   base += tot_edges * 4;
    int* gcount = (int*)base;                   base += (size_t)NBKT * 4;
    int* gbase  = (int*)base;                   base += (size_t)(NBKT + 1) * 4;
    int* gcur   = (int*)base;                   base += (size_t)NBKT * 4;
    int* gbinc  = (int*)base;                   base += 256 * 4;
    int* gcur256= (int*)base;                   base += 256 * 4;
    int* perm   = (int*)base;                   base += (size_t)ROWS * 4;
    int4* pA    = (int4*)base;                  base += (size_t)NP * 16;
    int2* pC    = (int2*)base;                  base += (size_t)NP * 8;
    int2* cinfo = (int2*)base;                  base += (size_t)NC * 8;

    float* out_c = (float*)d_out;
    float* out_p = out_c + CSZ;
    float* out_g = out_p + PSZ;
    float* out_b = out_g + (size_t)NG * 64;

    const int BT = 256;

    // ---- fused convert (also copies group/brand f32 outputs) ----
    const long long CVT = (long long)(NC + NP + NG + NB) * 8;
    convert_all<<<cdiv(CVT, BT), BT, 0, stream>>>(
        cust_w, prod_w, group_w, brand_w, c16A, p16A, g16, b16, out_g, out_b);

    // ---- CSR build: bucket-count -> bucket-scan -> multisplit -> bucket sort ----
    Edges6 E;
    E.src[0] = (const int*)d_in[4];  E.dst[0] = (const int*)d_in[5];
    E.src[1] = (const int*)d_in[6];  E.dst[1] = (const int*)d_in[7];
    E.src[2] = (const int*)d_in[8];  E.dst[2] = (const int*)d_in[9];
    E.src[3] = (const int*)d_in[10]; E.dst[3] = (const int*)d_in[11];
    E.src[4] = (const int*)d_in[12]; E.dst[4] = (const int*)d_in[13];
    E.src[5] = (const int*)d_in[14]; E.dst[5] = (const int*)d_in[15];
    E.cum[0] = 0;
    for (int k = 0; k < 6; ++k) E.cum[k + 1] = E.cum[k] + n_edges[k];
    const int TOT = E.cum[6];

    hipMemsetAsync(gcount, 0, (size_t)NBKT * 4, stream);
    hipMemsetAsync(gbinc, 0, 256 * 4, stream);
    bcount<<<cdiv(TOT, CH), BT, 0, stream>>>(E, gcount, TOT);
    bscan<<<1, SCAN_B, 0, stream>>>(gcount, gbase, gcur, NBKT);
    msplit<<<cdiv(TOT, CH), BT, 0, stream>>>(E, gcur, stage, TOT);
    sortb<<<NBKT, 512, 0, stream>>>(gbase, stage, pm_all, rp_all, RTOT);

    // ---- degree-balanced row permutation ----
    rowhist<<<cdiv(ROWS, RCH), 256, 0, stream>>>(rp_all, gbinc, ROWS);
    rowscan<<<1, 256, 0, stream>>>(gbinc, gcur256);
    rowplace<<<cdiv(ROWS, RCH), 256, 0, stream>>>(rp_all, gcur256, perm, ROWS);
    permrp<<<cdiv(ROWS, BT), BT, 0, stream>>>(rp_all, perm, pA, pC, cinfo, ROWS);

    // ---- 3 fused layers; d_out written only by layer 2 (deferred mean) ----
    const long long LTHREADS = (long long)ROWS * 8;
    layer_kernel<<<cdiv(LTHREADS, BT), BT, 0, stream>>>(
        perm, pA, pC, cinfo, pm_all,
        c16A, p16A, g16, b16, c16B, p16B,
        cust_w, prod_w, c16B, p16B, out_c, out_p, 0);
    layer_kernel<<<cdiv(LTHREADS, BT), BT, 0, stream>>>(
        perm, pA, pC, cinfo, pm_all,
        c16B, p16B, g16, b16, c16A, p16A,
        cust_w, prod_w, c16B, p16B, out_c, out_p, 1);
    layer_kernel<<<cdiv(LTHREADS, BT), BT, 0, stream>>>(
        perm, pA, pC, cinfo, pm_all,
        c16A, p16A, g16, b16, c16B, p16B,           // s2 = A (gather source)
        cust_w, prod_w, c16B, p16B,                 // s0 = inputs, s1 = B
        out_c, out_p, 2);
}

// Round 14
// 672.485 us; speedup vs baseline: 1.0106x; 1.0106x over previous
//
#include <hip/hip_runtime.h>

#define NC 300000
#define NP 150000
#define NG 2000
#define NB 500
#define SCAN_B 1024
#define BK_SHIFT 11
#define BK_KEYS 2048     // keys per bucket
#define CBASE (NC + 1)   // first product key
#define RTOT (CBASE + 5 * NP + 1)   // 1,050,002 keys (+ tail)
#define NBKT 513         // cdiv(RTOT, BK_KEYS)
#define CH 8192          // edges per chunk (bcount/msplit)
#define ROWS (NP + NC)   // 450,000 unified rows (product first)
#define RCH 4096         // rows per block in row-sort kernels

typedef unsigned int u32;
typedef float  f32x4 __attribute__((ext_vector_type(4)));
typedef unsigned int u32x4 __attribute__((ext_vector_type(4)));

static inline unsigned cdiv(long long a, long long b) { return (unsigned)((a + b - 1) / b); }

// ---------- bf16 helpers ----------
__device__ __forceinline__ float b2f(u32 h) {
    union { u32 u; float f; } c; c.u = h << 16; return c.f;
}
__device__ __forceinline__ u32 f2b(float f) {
    union { float f; u32 u; } c; c.f = f;
    return (c.u + 0x7FFFu + ((c.u >> 16) & 1u)) >> 16;   // RNE
}
__device__ __forceinline__ void unpack8(uint4 v, float* o) {
    o[0] = b2f(v.x & 0xFFFFu); o[1] = b2f(v.x >> 16);
    o[2] = b2f(v.y & 0xFFFFu); o[3] = b2f(v.y >> 16);
    o[4] = b2f(v.z & 0xFFFFu); o[5] = b2f(v.z >> 16);
    o[6] = b2f(v.w & 0xFFFFu); o[7] = b2f(v.w >> 16);
}
__device__ __forceinline__ void unpack8v(u32x4 v, float* o) {
    o[0] = b2f(v.x & 0xFFFFu); o[1] = b2f(v.x >> 16);
    o[2] = b2f(v.y & 0xFFFFu); o[3] = b2f(v.y >> 16);
    o[4] = b2f(v.z & 0xFFFFu); o[5] = b2f(v.z >> 16);
    o[6] = b2f(v.w & 0xFFFFu); o[7] = b2f(v.w >> 16);
}
__device__ __forceinline__ uint4 pack8(const float* a) {
    uint4 v;
    v.x = f2b(a[0]) | (f2b(a[1]) << 16);
    v.y = f2b(a[2]) | (f2b(a[3]) << 16);
    v.z = f2b(a[4]) | (f2b(a[5]) << 16);
    v.w = f2b(a[6]) | (f2b(a[7]) << 16);
    return v;
}

// ---------- fused CSR build over all 6 edge sets (row-major product keys) ----------
struct Edges6 {
    const int* src[6];
    const int* dst[6];
    int cum[7];      // cumulative edge-count offsets (cum[6] = total)
};

__device__ __forceinline__ int edge_key(int k, int src) {
    return (k == 0) ? src : CBASE + src * 5 + (k - 1);
}

// ---------- fused: f32->bf16 convert (blocks [0,nconv)) + bucket count (rest) ----------
// bcount section also persists its per-block histogram for msplit to reuse.
__global__ void conv_bcount(const float* __restrict__ cw, const float* __restrict__ pw,
                            const float* __restrict__ gw, const float* __restrict__ bw,
                            uint4* __restrict__ c16, uint4* __restrict__ p16,
                            uint4* __restrict__ g16, uint4* __restrict__ b16,
                            float* __restrict__ outg, float* __restrict__ outb,
                            Edges6 e, int* __restrict__ gcount, int* __restrict__ bhist,
                            int total, int nconv) {
    __shared__ int hist[NBKT];
    int t = threadIdx.x;
    if ((int)blockIdx.x < nconv) {
        const int C8 = NC * 8, P8 = NP * 8, G8 = NG * 8, B8 = NB * 8;
        int i = blockIdx.x * blockDim.x + t;
        const float* in; uint4* out16; float* cpy = nullptr; int j;
        if (i < C8)                          { in = cw; out16 = c16; j = i; }
        else if ((j = i - C8) < P8)          { in = pw; out16 = p16; }
        else if ((j = i - C8 - P8) < G8)     { in = gw; out16 = g16; cpy = outg; }
        else if ((j = i - C8 - P8 - G8) < B8){ in = bw; out16 = b16; cpy = outb; }
        else return;
        const float4* p = (const float4*)(in + (size_t)j * 8);
        float4 a = p[0], b = p[1];
        float tv[8] = { a.x, a.y, a.z, a.w, b.x, b.y, b.z, b.w };
        out16[j] = pack8(tv);
        if (cpy) { float4* q = (float4*)(cpy + (size_t)j * 8); q[0] = a; q[1] = b; }
        return;
    }
    int blk = blockIdx.x - nconv;
    int j0 = blk * CH;
    for (int b = t; b < NBKT; b += blockDim.x) hist[b] = 0;
    __syncthreads();
    #pragma unroll 4
    for (int q = 0; q < CH / 256; ++q) {
        int j = j0 + q * 256 + t;
        if (j < total) {
            int k = 0;
            #pragma unroll
            for (int qq = 1; qq < 6; ++qq) k += (j >= e.cum[qq]);
            int key = edge_key(k, __builtin_nontemporal_load(e.src[k] + (j - e.cum[k])));
            atomicAdd(&hist[key >> BK_SHIFT], 1);
        }
    }
    __syncthreads();
    int* bh = bhist + (size_t)blk * NBKT;
    for (int b = t; b < NBKT; b += blockDim.x) {
        int c = hist[b];
        bh[b] = c;
        if (c > 0) atomicAdd(gcount + b, c);
    }
}

// ---------- stage B: one-block scan of bucket counts -> gbase, gcur ----------
__global__ void bscan(const int* __restrict__ gcount, int* __restrict__ gbase,
                      int* __restrict__ gcur, int nb) {
    __shared__ int sm[SCAN_B];
    int t = threadIdx.x;
    int v = (t < nb) ? gcount[t] : 0;
    sm[t] = v; __syncthreads();
    for (int off = 1; off < SCAN_B; off <<= 1) {
        int add = (t >= off) ? sm[t - off] : 0;
        __syncthreads();
        sm[t] += add; __syncthreads();
    }
    int excl = sm[t] - v;
    if (t < nb) { gbase[t] = excl; gcur[t] = excl; }
    if (t == nb - 1) gbase[nb] = sm[t];
}

// ---------- stage C: multisplit using persisted histograms (claim + place only) ----------
// stage word = (key & 2047) << 19 | dst   (dst < 2^19)
__global__ void msplit(Edges6 e, int* __restrict__ gcur, const int* __restrict__ bhist,
                       u32* __restrict__ stage, int total) {
    __shared__ int hist[NBKT];
    __shared__ int bse[NBKT];
    int t = threadIdx.x;
    int j0 = blockIdx.x * CH;
    const int* bh = bhist + (size_t)blockIdx.x * NBKT;
    for (int b = t; b < NBKT; b += blockDim.x) {
        int c = bh[b];
        bse[b] = (c > 0) ? atomicAdd(gcur + b, c) : 0;
        hist[b] = 0;
    }
    __syncthreads();
    #pragma unroll 4
    for (int q = 0; q < CH / 256; ++q) {
        int j = j0 + q * 256 + t;
        if (j < total) {
            int k = 0;
            #pragma unroll
            for (int qq = 1; qq < 6; ++qq) k += (j >= e.cum[qq]);
            int jj = j - e.cum[k];
            int key = edge_key(k, __builtin_nontemporal_load(e.src[k] + jj));
            int d = __builtin_nontemporal_load(e.dst[k] + jj);
            int b = key >> BK_SHIFT;
            int off = atomicAdd(&hist[b], 1);
            stage[bse[b] + off] = ((u32)(key & (BK_KEYS - 1)) << 19) | (u32)d;
        }
    }
}

// ---------- stage D: per-bucket LDS histogram+scan -> rowptr slice + place pm ----------
__global__ void sortb(const int* __restrict__ gbase, const u32* __restrict__ stage,
                      int* __restrict__ pm, int* __restrict__ rp, int rtot) {
    __shared__ int cur[BK_KEYS];
    __shared__ int part[512];
    int b = blockIdx.x, t = threadIdx.x;
    int k0 = b << BK_SHIFT;
    int base = gbase[b], end = gbase[b + 1];
    for (int q = t; q < BK_KEYS; q += 512) cur[q] = 0;
    __syncthreads();
    for (int i = base + t; i < end; i += 512)
        atomicAdd(&cur[stage[i] >> 19], 1);
    __syncthreads();
    int a0 = cur[4 * t], a1 = cur[4 * t + 1], a2 = cur[4 * t + 2], a3 = cur[4 * t + 3];
    int s = a0 + a1 + a2 + a3;
    part[t] = s; __syncthreads();
    for (int off = 1; off < 512; off <<= 1) {
        int add = (t >= off) ? part[t - off] : 0;
        __syncthreads();
        part[t] += add; __syncthreads();
    }
    int c0 = base + part[t] - s;
    int c1 = c0 + a0, c2 = c1 + a1, c3 = c2 + a2;
    cur[4 * t] = c0; cur[4 * t + 1] = c1; cur[4 * t + 2] = c2; cur[4 * t + 3] = c3;
    int ki = k0 + 4 * t;
    if (ki + 3 < rtot) {
        *(int4*)(rp + ki) = make_int4(c0, c1, c2, c3);
    } else {
        if (ki     < rtot) rp[ki]     = c0;
        if (ki + 1 < rtot) rp[ki + 1] = c1;
        if (ki + 2 < rtot) rp[ki + 2] = c2;
        if (ki + 3 < rtot) rp[ki + 3] = c3;
    }
    __syncthreads();
    for (int i = base + t; i < end; i += 512) {
        u32 w = stage[i];
        int off = atomicAdd(&cur[w >> 19], 1);
        pm[off] = (int)(w & 0x7FFFFu);
    }
}

// ---------- row workload bin: product rows 0..127, customer rows 128..255 ----------
__device__ __forceinline__ int row_bin(const int* __restrict__ rp, int gid) {
    if (gid < NP) {
        int o = CBASE + gid * 5;
        int td = rp[o + 5] - rp[o];           // merged run length
        return td < 127 ? td : 127;
    } else {
        int r = gid - NP;
        int d = rp[r + 1] - rp[r];
        return 128 + (d < 127 ? d : 127);
    }
}

__global__ void rowhist(const int* __restrict__ rp, int* __restrict__ gbinc, int rows) {
    __shared__ int hist[256];
    int t = threadIdx.x;
    hist[t] = 0;
    __syncthreads();
    int j0 = blockIdx.x * RCH;
    for (int q = 0; q < RCH / 256; ++q) {
        int j = j0 + q * 256 + t;
        if (j < rows) atomicAdd(&hist[row_bin(rp, j)], 1);
    }
    __syncthreads();
    int c = hist[t];
    if (c > 0) atomicAdd(gbinc + t, c);
}

__global__ void rowscan(const int* __restrict__ gbinc, int* __restrict__ gcur256) {
    __shared__ int sm[256];
    int t = threadIdx.x;
    int v = gbinc[t];
    sm[t] = v; __syncthreads();
    for (int off = 1; off < 256; off <<= 1) {
        int add = (t >= off) ? sm[t - off] : 0;
        __syncthreads();
        sm[t] += add; __syncthreads();
    }
    gcur256[t] = sm[t] - v;
}

__global__ void rowplace(const int* __restrict__ rp, int* __restrict__ gcur256,
                         int* __restrict__ perm, int rows) {
    __shared__ int hist[256];
    __shared__ int bse[256];
    int t = threadIdx.x;
    hist[t] = 0;
    __syncthreads();
    int j0 = blockIdx.x * RCH;
    for (int q = 0; q < RCH / 256; ++q) {
        int j = j0 + q * 256 + t;
        if (j < rows) atomicAdd(&hist[row_bin(rp, j)], 1);
    }
    __syncthreads();
    int c = hist[t];
    bse[t] = (c > 0) ? atomicAdd(gcur256 + t, c) : 0;
    hist[t] = 0;
    __syncthreads();
    for (int q = 0; q < RCH / 256; ++q) {
        int j = j0 + q * 256 + t;
        if (j < rows) {
            int b = row_bin(rp, j);
            int off = atomicAdd(&hist[b], 1);
            perm[bse[b] + off] = j;
        }
    }
}

// materialize permuted segment bounds: product = 6 contiguous rp values
__global__ void permrp(const int* __restrict__ rp, const int* __restrict__ perm,
                       int4* __restrict__ pA, int2* __restrict__ pC,
                       int2* __restrict__ cinfo, int rows) {
    int j = blockIdx.x * blockDim.x + threadIdx.x;
    if (j >= rows) return;
    int pg = perm[j];
    if (pg < NP) {
        const int* r0 = rp + CBASE + pg * 5;
        pA[j] = make_int4(r0[0], r0[1], r0[2], r0[3]);
        pC[j] = make_int2(r0[4], r0[5]);
    } else {
        int r = pg - NP;
        cinfo[j - NP] = make_int2(rp[r], rp[r + 1]);
    }
}

// ---------- customer-side mean-agg (single segment) ----------
__device__ __forceinline__ void acc8(uint4 v, float* sum) {
    float t[8]; unpack8(v, t);
    #pragma unroll
    for (int k = 0; k < 8; ++k) sum[k] += t[k];
}
__device__ __forceinline__ void agg8se(int s, int e, const int* __restrict__ pm,
                                       const uint4* __restrict__ tgt,
                                       int lane, float* acc) {
    float sum[8] = {0, 0, 0, 0, 0, 0, 0, 0};
    int i = s;
    for (; i + 4 <= e; i += 4) {
        int d0 = pm[i], d1 = pm[i + 1], d2 = pm[i + 2], d3 = pm[i + 3];
        uint4 v0 = tgt[(size_t)d0 * 8 + lane];
        uint4 v1 = tgt[(size_t)d1 * 8 + lane];
        uint4 v2 = tgt[(size_t)d2 * 8 + lane];
        uint4 v3 = tgt[(size_t)d3 * 8 + lane];
        acc8(v0, sum); acc8(v1, sum); acc8(v2, sum); acc8(v3, sum);
    }
    for (; i < e; ++i) {
        uint4 v = tgt[(size_t)pm[i] * 8 + lane];
        acc8(v, sum);
    }
    int deg = e - s;
    float sc = 1.0f / (float)(deg > 1 ? deg : 1);
    #pragma unroll
    for (int k = 0; k < 8; ++k) acc[k] += sum[k] * sc;
}

// per-edge table/scale select for the merged product run
__device__ __forceinline__ const uint4* tblsel(int i, int b1, int b3, int b4,
                                               const uint4* c16, const uint4* p16,
                                               const uint4* g16, const uint4* b16) {
    const uint4* t = c16;
    if (i >= b1) t = p16;     // sim & cop both read p16
    if (i >= b3) t = g16;
    if (i >= b4) t = b16;
    return t;
}
__device__ __forceinline__ float sclsel(int i, int b1, int b2, int b3, int b4,
                                        float s0, float s1, float s2, float s3, float s4) {
    float s = s0;
    if (i >= b1) s = s1;
    if (i >= b2) s = s2;
    if (i >= b3) s = s3;
    if (i >= b4) s = s4;
    return s;
}
__device__ __forceinline__ void accw(uint4 v, float s, float* acc) {
    float t[8]; unpack8(v, t);
    #pragma unroll
    for (int k = 0; k < 8; ++k) acc[k] += t[k] * s;
}

// ---------- fused layer (degree-balanced rows, merged product runs) ----------
// modes 0/1: write next-snapshot only. mode 2: out = 0.25*(s0+s1+s2+acc).
__global__ void layer_kernel(
    const int* __restrict__ perm,
    const int4* __restrict__ pA, const int2* __restrict__ pC,
    const int2* __restrict__ cinfo,
    const int* __restrict__ pm,
    const uint4* __restrict__ c16, const uint4* __restrict__ p16,
    const uint4* __restrict__ g16, const uint4* __restrict__ b16,
    uint4* __restrict__ c16n, uint4* __restrict__ p16n,
    const float* __restrict__ cw, const float* __restrict__ pw,
    const uint4* __restrict__ s1c, const uint4* __restrict__ s1p,
    float* __restrict__ outc, float* __restrict__ outp,
    int mode)
{
    int t = blockIdx.x * blockDim.x + threadIdx.x;
    int gid = t >> 3;
    int lane = t & 7;
    float acc[8];
    if (gid < NP) {
        int row = perm[gid];                      // original product row
        size_t idx = (size_t)row * 8 + lane;
        int4 ia = pA[gid];
        int2 ic = pC[gid];
        int b0 = ia.x, b1 = ia.y, b2 = ia.z, b3 = ia.w, b4 = ic.x, b5 = ic.y;
        int d0g = b1 - b0, d1g = b2 - b1, d2g = b3 - b2, d3g = b4 - b3, d4g = b5 - b4;
        float s0 = 1.0f / (float)(d0g > 1 ? d0g : 1);
        float s1 = 0.5f / (float)(d1g > 1 ? d1g : 1);
        float s2 = 0.3f / (float)(d2g > 1 ? d2g : 1);
        float s3 = 0.2f / (float)(d3g > 1 ? d3g : 1);
        float s4 = 0.2f / (float)(d4g > 1 ? d4g : 1);
        float base[8]; unpack8(p16[idx], base);
        #pragma unroll
        for (int k = 0; k < 8; ++k) acc[k] = base[k];
        int i = b0;
        for (; i + 4 <= b5; i += 4) {
            int e0 = pm[i], e1 = pm[i + 1], e2 = pm[i + 2], e3 = pm[i + 3];
            const uint4* t0 = tblsel(i,     b1, b3, b4, c16, p16, g16, b16);
            const uint4* t1 = tblsel(i + 1, b1, b3, b4, c16, p16, g16, b16);
            const uint4* t2 = tblsel(i + 2, b1, b3, b4, c16, p16, g16, b16);
            const uint4* t3 = tblsel(i + 3, b1, b3, b4, c16, p16, g16, b16);
            float w0 = sclsel(i,     b1, b2, b3, b4, s0, s1, s2, s3, s4);
            float w1 = sclsel(i + 1, b1, b2, b3, b4, s0, s1, s2, s3, s4);
            float w2 = sclsel(i + 2, b1, b2, b3, b4, s0, s1, s2, s3, s4);
            float w3 = sclsel(i + 3, b1, b2, b3, b4, s0, s1, s2, s3, s4);
            uint4 v0 = t0[(size_t)e0 * 8 + lane];
            uint4 v1 = t1[(size_t)e1 * 8 + lane];
            uint4 v2 = t2[(size_t)e2 * 8 + lane];
            uint4 v3 = t3[(size_t)e3 * 8 + lane];
            accw(v0, w0, acc); accw(v1, w1, acc); accw(v2, w2, acc); accw(v3, w3, acc);
        }
        for (; i < b5; ++i) {
            int e0 = pm[i];
            const uint4* t0 = tblsel(i, b1, b3, b4, c16, p16, g16, b16);
            float w0 = sclsel(i, b1, b2, b3, b4, s0, s1, s2, s3, s4);
            uint4 v0 = t0[(size_t)e0 * 8 + lane];
            accw(v0, w0, acc);
        }
        if (mode != 2) {
            p16n[idx] = pack8(acc);
        } else {
            const f32x4* s0p = (const f32x4*)(pw + (size_t)row * 64 + lane * 8);
            f32x4 a0 = __builtin_nontemporal_load(s0p);
            f32x4 a1 = __builtin_nontemporal_load(s0p + 1);
            u32x4 s1v = __builtin_nontemporal_load((const u32x4*)&s1p[idx]);
            float sv[8]; unpack8v(s1v, sv);
            f32x4 o0, o1;
            o0.x = 0.25f * (a0.x + sv[0] + base[0] + acc[0]);
            o0.y = 0.25f * (a0.y + sv[1] + base[1] + acc[1]);
            o0.z = 0.25f * (a0.z + sv[2] + base[2] + acc[2]);
            o0.w = 0.25f * (a0.w + sv[3] + base[3] + acc[3]);
            o1.x = 0.25f * (a1.x + sv[4] + base[4] + acc[4]);
            o1.y = 0.25f * (a1.y + sv[5] + base[5] + acc[5]);
            o1.z = 0.25f * (a1.z + sv[6] + base[6] + acc[6]);
            o1.w = 0.25f * (a1.w + sv[7] + base[7] + acc[7]);
            f32x4* o = (f32x4*)(outp + (size_t)row * 64 + lane * 8);
            __builtin_nontemporal_store(o0, o);
            __builtin_nontemporal_store(o1, o + 1);
        }
    } else if (gid < ROWS) {
        int row = perm[gid] - NP;                 // original customer row
        size_t idx = (size_t)row * 8 + lane;
        int2 se = cinfo[gid - NP];
        #pragma unroll
        for (int k = 0; k < 8; ++k) acc[k] = 0.f;
        agg8se(se.x, se.y, pm, p16, lane, acc);
        if (mode != 2) {
            c16n[idx] = pack8(acc);
        } else {
            float base[8]; unpack8(c16[idx], base);                       // s2
            const f32x4* s0c = (const f32x4*)(cw + (size_t)row * 64 + lane * 8);
            f32x4 a0 = __builtin_nontemporal_load(s0c);
            f32x4 a1 = __builtin_nontemporal_load(s0c + 1);
            u32x4 s1v = __builtin_nontemporal_load((const u32x4*)&s1c[idx]);
            float sv[8]; unpack8v(s1v, sv);                               // s1
            f32x4 o0, o1;
            o0.x = 0.25f * (a0.x + sv[0] + base[0] + acc[0]);
            o0.y = 0.25f * (a0.y + sv[1] + base[1] + acc[1]);
            o0.z = 0.25f * (a0.z + sv[2] + base[2] + acc[2]);
            o0.w = 0.25f * (a0.w + sv[3] + base[3] + acc[3]);
            o1.x = 0.25f * (a1.x + sv[4] + base[4] + acc[4]);
            o1.y = 0.25f * (a1.y + sv[5] + base[5] + acc[5]);
            o1.z = 0.25f * (a1.z + sv[6] + base[6] + acc[6]);
            o1.w = 0.25f * (a1.w + sv[7] + base[7] + acc[7]);
            f32x4* o = (f32x4*)(outc + (size_t)row * 64 + lane * 8);
            __builtin_nontemporal_store(o0, o);
            __builtin_nontemporal_store(o1, o + 1);
        }
    }
}

extern "C" void kernel_launch(void* const* d_in, const int* in_sizes, int n_in,
                              void* d_out, int out_size, void* d_ws, size_t ws_size,
                              hipStream_t stream) {
    const float* cust_w  = (const float*)d_in[0];
    const float* prod_w  = (const float*)d_in[1];
    const float* group_w = (const float*)d_in[2];
    const float* brand_w = (const float*)d_in[3];

    const int n_purch = in_sizes[4];
    const int n_pby   = in_sizes[6];
    const int n_sim   = in_sizes[8];
    const int n_cop   = in_sizes[10];
    const int n_bel   = in_sizes[12];
    const int n_comp  = in_sizes[14];
    const int n_edges[6] = { n_purch, n_pby, n_sim, n_cop, n_bel, n_comp };

    const size_t CSZ = (size_t)NC * 64;
    const size_t PSZ = (size_t)NP * 64;

    // ---- workspace layout ----
    char* base = (char*)d_ws;
    uint4* c16A = (uint4*)base;                 base += (size_t)NC * 128;
    uint4* c16B = (uint4*)base;                 base += (size_t)NC * 128;
    uint4* p16A = (uint4*)base;                 base += (size_t)NP * 128;
    uint4* p16B = (uint4*)base;                 base += (size_t)NP * 128;
    uint4* g16  = (uint4*)base;                 base += (size_t)NG * 128;
    uint4* b16  = (uint4*)base;                 base += (size_t)NB * 128;

    int* rp_all = (int*)base;                   base += (size_t)RTOT * 4;
    long long tot_edges = 0;
    for (int k = 0; k < 6; ++k) tot_edges += n_edges[k];
    int* pm_all = (int*)base;                   base += tot_edges * 4;
    u32* stage  = (u32*)base;                   base += tot_edges * 4;
    const int NEDGE = cdiv(tot_edges, CH);
    int* bhist  = (int*)base;                   base += (size_t)NEDGE * NBKT * 4;
    int* gcount = (int*)base;                   base += (size_t)NBKT * 4;
    int* gbase  = (int*)base;                   base += (size_t)(NBKT + 1) * 4;
    int* gcur   = (int*)base;                   base += (size_t)NBKT * 4;
    int* gbinc  = (int*)base;                   base += 256 * 4;
    int* gcur256= (int*)base;                   base += 256 * 4;
    int* perm   = (int*)base;                   base += (size_t)ROWS * 4;
    int4* pA    = (int4*)base;                  base += (size_t)NP * 16;
    int2* pC    = (int2*)base;                  base += (size_t)NP * 8;
    int2* cinfo = (int2*)base;                  base += (size_t)NC * 8;

    float* out_c = (float*)d_out;
    float* out_p = out_c + CSZ;
    float* out_g = out_p + PSZ;
    float* out_b = out_g + (size_t)NG * 64;

    const int BT = 256;

    // ---- edge descriptor ----
    Edges6 E;
    E.src[0] = (const int*)d_in[4];  E.dst[0] = (const int*)d_in[5];
    E.src[1] = (const int*)d_in[6];  E.dst[1] = (const int*)d_in[7];
    E.src[2] = (const int*)d_in[8];  E.dst[2] = (const int*)d_in[9];
    E.src[3] = (const int*)d_in[10]; E.dst[3] = (const int*)d_in[11];
    E.src[4] = (const int*)d_in[12]; E.dst[4] = (const int*)d_in[13];
    E.src[5] = (const int*)d_in[14]; E.dst[5] = (const int*)d_in[15];
    E.cum[0] = 0;
    for (int k = 0; k < 6; ++k) E.cum[k + 1] = E.cum[k] + n_edges[k];
    const int TOT = E.cum[6];

    hipMemsetAsync(gcount, 0, (size_t)NBKT * 4, stream);
    hipMemsetAsync(gbinc, 0, 256 * 4, stream);

    // ---- fused convert + bucket-count (overlapped in one launch) ----
    const long long CVT = (long long)(NC + NP + NG + NB) * 8;
    const int NCONV = cdiv(CVT, BT);
    conv_bcount<<<NCONV + NEDGE, BT, 0, stream>>>(
        cust_w, prod_w, group_w, brand_w, c16A, p16A, g16, b16, out_g, out_b,
        E, gcount, bhist, TOT, NCONV);

    bscan<<<1, SCAN_B, 0, stream>>>(gcount, gbase, gcur, NBKT);
    msplit<<<NEDGE, BT, 0, stream>>>(E, gcur, bhist, stage, TOT);
    sortb<<<NBKT, 512, 0, stream>>>(gbase, stage, pm_all, rp_all, RTOT);

    // ---- degree-balanced row permutation ----
    rowhist<<<cdiv(ROWS, RCH), 256, 0, stream>>>(rp_all, gbinc, ROWS);
    rowscan<<<1, 256, 0, stream>>>(gbinc, gcur256);
    rowplace<<<cdiv(ROWS, RCH), 256, 0, stream>>>(rp_all, gcur256, perm, ROWS);
    permrp<<<cdiv(ROWS, BT), BT, 0, stream>>>(rp_all, perm, pA, pC, cinfo, ROWS);

    // ---- 3 fused layers; d_out written only by layer 2 (deferred mean) ----
    const long long LTHREADS = (long long)ROWS * 8;
    layer_kernel<<<cdiv(LTHREADS, BT), BT, 0, stream>>>(
        perm, pA, pC, cinfo, pm_all,
        c16A, p16A, g16, b16, c16B, p16B,
        cust_w, prod_w, c16B, p16B, out_c, out_p, 0);
    layer_kernel<<<cdiv(LTHREADS, BT), BT, 0, stream>>>(
        perm, pA, pC, cinfo, pm_all,
        c16B, p16B, g16, b16, c16A, p16A,
        cust_w, prod_w, c16B, p16B, out_c, out_p, 1);
    layer_kernel<<<cdiv(LTHREADS, BT), BT, 0, stream>>>(
        perm, pA, pC, cinfo, pm_all,
        c16A, p16A, g16, b16, c16B, p16B,           // s2 = A (gather source)
        cust_w, prod_w, c16B, p16B,                 // s0 = inputs, s1 = B
        out_c, out_p, 2);
}

// Round 15
// 664.231 us; speedup vs baseline: 1.0231x; 1.0124x over previous
//
#include <hip/hip_runtime.h>

#define NC 300000
#define NP 150000
#define NG 2000
#define NB 500
#define SCAN_B 1024
#define BK_SHIFT 11
#define BK_KEYS 2048     // keys per bucket
#define CBASE (NC + 1)   // first product key
#define RTOT (CBASE + 5 * NP + 1)   // 1,050,002 keys (+ tail)
#define NBKT 513         // cdiv(RTOT, BK_KEYS)
#define CH 8192          // edges per chunk (bcount/msplit)
#define ROWS (NP + NC)   // 450,000 unified rows (product first)
#define RCH 4096         // rows per block in row-sort kernels

typedef unsigned int u32;
typedef float  f32x4 __attribute__((ext_vector_type(4)));
typedef unsigned int u32x4 __attribute__((ext_vector_type(4)));

static inline unsigned cdiv(long long a, long long b) { return (unsigned)((a + b - 1) / b); }

// ---------- bf16 helpers ----------
__device__ __forceinline__ float b2f(u32 h) {
    union { u32 u; float f; } c; c.u = h << 16; return c.f;
}
__device__ __forceinline__ u32 f2b(float f) {
    union { float f; u32 u; } c; c.f = f;
    return (c.u + 0x7FFFu + ((c.u >> 16) & 1u)) >> 16;   // RNE
}
__device__ __forceinline__ void unpack8(uint4 v, float* o) {
    o[0] = b2f(v.x & 0xFFFFu); o[1] = b2f(v.x >> 16);
    o[2] = b2f(v.y & 0xFFFFu); o[3] = b2f(v.y >> 16);
    o[4] = b2f(v.z & 0xFFFFu); o[5] = b2f(v.z >> 16);
    o[6] = b2f(v.w & 0xFFFFu); o[7] = b2f(v.w >> 16);
}
__device__ __forceinline__ void unpack8v(u32x4 v, float* o) {
    o[0] = b2f(v.x & 0xFFFFu); o[1] = b2f(v.x >> 16);
    o[2] = b2f(v.y & 0xFFFFu); o[3] = b2f(v.y >> 16);
    o[4] = b2f(v.z & 0xFFFFu); o[5] = b2f(v.z >> 16);
    o[6] = b2f(v.w & 0xFFFFu); o[7] = b2f(v.w >> 16);
}
__device__ __forceinline__ uint4 pack8(const float* a) {
    uint4 v;
    v.x = f2b(a[0]) | (f2b(a[1]) << 16);
    v.y = f2b(a[2]) | (f2b(a[3]) << 16);
    v.z = f2b(a[4]) | (f2b(a[5]) << 16);
    v.w = f2b(a[6]) | (f2b(a[7]) << 16);
    return v;
}

// ---------- fused CSR build over all 6 edge sets (row-major product keys) ----------
struct Edges6 {
    const int* src[6];
    const int* dst[6];
    int cum[7];      // cumulative edge-count offsets (cum[6] = total)
};

__device__ __forceinline__ int edge_key(int k, int src) {
    return (k == 0) ? src : CBASE + src * 5 + (k - 1);
}

// ---------- fused: f32->bf16 convert (blocks [0,nconv)) + bucket count (rest) ----------
__global__ void conv_bcount(const float* __restrict__ cw, const float* __restrict__ pw,
                            const float* __restrict__ gw, const float* __restrict__ bw,
                            uint4* __restrict__ c16, uint4* __restrict__ p16,
                            uint4* __restrict__ g16, uint4* __restrict__ b16,
                            float* __restrict__ outg, float* __restrict__ outb,
                            Edges6 e, int* __restrict__ gcount, int* __restrict__ bhist,
                            int total, int nconv) {
    __shared__ int hist[NBKT];
    int t = threadIdx.x;
    if ((int)blockIdx.x < nconv) {
        const int C8 = NC * 8, P8 = NP * 8, G8 = NG * 8, B8 = NB * 8;
        int i = blockIdx.x * blockDim.x + t;
        const float* in; uint4* out16; float* cpy = nullptr; int j;
        if (i < C8)                          { in = cw; out16 = c16; j = i; }
        else if ((j = i - C8) < P8)          { in = pw; out16 = p16; }
        else if ((j = i - C8 - P8) < G8)     { in = gw; out16 = g16; cpy = outg; }
        else if ((j = i - C8 - P8 - G8) < B8){ in = bw; out16 = b16; cpy = outb; }
        else return;
        const float4* p = (const float4*)(in + (size_t)j * 8);
        float4 a = p[0], b = p[1];
        float tv[8] = { a.x, a.y, a.z, a.w, b.x, b.y, b.z, b.w };
        out16[j] = pack8(tv);
        if (cpy) { float4* q = (float4*)(cpy + (size_t)j * 8); q[0] = a; q[1] = b; }
        return;
    }
    int blk = blockIdx.x - nconv;
    int j0 = blk * CH;
    for (int b = t; b < NBKT; b += blockDim.x) hist[b] = 0;
    __syncthreads();
    #pragma unroll 4
    for (int q = 0; q < CH / 256; ++q) {
        int j = j0 + q * 256 + t;
        if (j < total) {
            int k = 0;
            #pragma unroll
            for (int qq = 1; qq < 6; ++qq) k += (j >= e.cum[qq]);
            int key = edge_key(k, __builtin_nontemporal_load(e.src[k] + (j - e.cum[k])));
            atomicAdd(&hist[key >> BK_SHIFT], 1);
        }
    }
    __syncthreads();
    int* bh = bhist + (size_t)blk * NBKT;
    for (int b = t; b < NBKT; b += blockDim.x) {
        int c = hist[b];
        bh[b] = c;
        if (c > 0) atomicAdd(gcount + b, c);
    }
}

// ---------- stage B: one-block scan of bucket counts -> gbase, gcur ----------
__global__ void bscan(const int* __restrict__ gcount, int* __restrict__ gbase,
                      int* __restrict__ gcur, int nb) {
    __shared__ int sm[SCAN_B];
    int t = threadIdx.x;
    int v = (t < nb) ? gcount[t] : 0;
    sm[t] = v; __syncthreads();
    for (int off = 1; off < SCAN_B; off <<= 1) {
        int add = (t >= off) ? sm[t - off] : 0;
        __syncthreads();
        sm[t] += add; __syncthreads();
    }
    int excl = sm[t] - v;
    if (t < nb) { gbase[t] = excl; gcur[t] = excl; }
    if (t == nb - 1) gbase[nb] = sm[t];
}

// ---------- stage C: multisplit using persisted histograms (claim + place only) ----------
// stage word = (key & 2047) << 19 | dst   (dst < 2^19)
__global__ void msplit(Edges6 e, int* __restrict__ gcur, const int* __restrict__ bhist,
                       u32* __restrict__ stage, int total) {
    __shared__ int hist[NBKT];
    __shared__ int bse[NBKT];
    int t = threadIdx.x;
    int j0 = blockIdx.x * CH;
    const int* bh = bhist + (size_t)blockIdx.x * NBKT;
    for (int b = t; b < NBKT; b += blockDim.x) {
        int c = bh[b];
        bse[b] = (c > 0) ? atomicAdd(gcur + b, c) : 0;
        hist[b] = 0;
    }
    __syncthreads();
    #pragma unroll 4
    for (int q = 0; q < CH / 256; ++q) {
        int j = j0 + q * 256 + t;
        if (j < total) {
            int k = 0;
            #pragma unroll
            for (int qq = 1; qq < 6; ++qq) k += (j >= e.cum[qq]);
            int jj = j - e.cum[k];
            int key = edge_key(k, __builtin_nontemporal_load(e.src[k] + jj));
            int d = __builtin_nontemporal_load(e.dst[k] + jj);
            int b = key >> BK_SHIFT;
            int off = atomicAdd(&hist[b], 1);
            stage[bse[b] + off] = ((u32)(key & (BK_KEYS - 1)) << 19) | (u32)d;
        }
    }
}

// ---------- stage D: per-bucket LDS histogram+scan -> rowptr slice + place pm ----------
__global__ void sortb(const int* __restrict__ gbase, const u32* __restrict__ stage,
                      int* __restrict__ pm, int* __restrict__ rp, int rtot) {
    __shared__ int cur[BK_KEYS];
    __shared__ int part[512];
    int b = blockIdx.x, t = threadIdx.x;
    int k0 = b << BK_SHIFT;
    int base = gbase[b], end = gbase[b + 1];
    for (int q = t; q < BK_KEYS; q += 512) cur[q] = 0;
    __syncthreads();
    for (int i = base + t; i < end; i += 512)
        atomicAdd(&cur[stage[i] >> 19], 1);
    __syncthreads();
    int a0 = cur[4 * t], a1 = cur[4 * t + 1], a2 = cur[4 * t + 2], a3 = cur[4 * t + 3];
    int s = a0 + a1 + a2 + a3;
    part[t] = s; __syncthreads();
    for (int off = 1; off < 512; off <<= 1) {
        int add = (t >= off) ? part[t - off] : 0;
        __syncthreads();
        part[t] += add; __syncthreads();
    }
    int c0 = base + part[t] - s;
    int c1 = c0 + a0, c2 = c1 + a1, c3 = c2 + a2;
    cur[4 * t] = c0; cur[4 * t + 1] = c1; cur[4 * t + 2] = c2; cur[4 * t + 3] = c3;
    int ki = k0 + 4 * t;
    if (ki + 3 < rtot) {
        *(int4*)(rp + ki) = make_int4(c0, c1, c2, c3);
    } else {
        if (ki     < rtot) rp[ki]     = c0;
        if (ki + 1 < rtot) rp[ki + 1] = c1;
        if (ki + 2 < rtot) rp[ki + 2] = c2;
        if (ki + 3 < rtot) rp[ki + 3] = c3;
    }
    __syncthreads();
    for (int i = base + t; i < end; i += 512) {
        u32 w = stage[i];
        int off = atomicAdd(&cur[w >> 19], 1);
        pm[off] = (int)(w & 0x7FFFFu);
    }
}

// ---------- row workload bin: product rows 0..127, customer rows 128..255 ----------
__device__ __forceinline__ int row_bin(const int* __restrict__ rp, int gid) {
    if (gid < NP) {
        int o = CBASE + gid * 5;
        int td = rp[o + 5] - rp[o];           // merged run length
        return td < 127 ? td : 127;
    } else {
        int r = gid - NP;
        int d = rp[r + 1] - rp[r];
        return 128 + (d < 127 ? d : 127);
    }
}

__global__ void rowhist(const int* __restrict__ rp, int* __restrict__ gbinc, int rows) {
    __shared__ int hist[256];
    int t = threadIdx.x;
    hist[t] = 0;
    __syncthreads();
    int j0 = blockIdx.x * RCH;
    for (int q = 0; q < RCH / 256; ++q) {
        int j = j0 + q * 256 + t;
        if (j < rows) atomicAdd(&hist[row_bin(rp, j)], 1);
    }
    __syncthreads();
    int c = hist[t];
    if (c > 0) atomicAdd(gbinc + t, c);
}

__global__ void rowscan(const int* __restrict__ gbinc, int* __restrict__ gcur256) {
    __shared__ int sm[256];
    int t = threadIdx.x;
    int v = gbinc[t];
    sm[t] = v; __syncthreads();
    for (int off = 1; off < 256; off <<= 1) {
        int add = (t >= off) ? sm[t - off] : 0;
        __syncthreads();
        sm[t] += add; __syncthreads();
    }
    gcur256[t] = sm[t] - v;
}

// placement + direct materialization of permuted bounds (permrp folded in)
__global__ void rowplace(const int* __restrict__ rp, int* __restrict__ gcur256,
                         int* __restrict__ perm,
                         int4* __restrict__ pA, int2* __restrict__ pC,
                         int2* __restrict__ cinfo, int rows) {
    __shared__ int hist[256];
    __shared__ int bse[256];
    int t = threadIdx.x;
    hist[t] = 0;
    __syncthreads();
    int j0 = blockIdx.x * RCH;
    for (int q = 0; q < RCH / 256; ++q) {
        int j = j0 + q * 256 + t;
        if (j < rows) atomicAdd(&hist[row_bin(rp, j)], 1);
    }
    __syncthreads();
    int c = hist[t];
    bse[t] = (c > 0) ? atomicAdd(gcur256 + t, c) : 0;
    hist[t] = 0;
    __syncthreads();
    for (int q = 0; q < RCH / 256; ++q) {
        int j = j0 + q * 256 + t;
        if (j < rows) {
            int b = row_bin(rp, j);
            int off = atomicAdd(&hist[b], 1);
            int slot = bse[b] + off;
            perm[slot] = j;
            if (j < NP) {
                const int* r0 = rp + CBASE + j * 5;
                pA[slot] = make_int4(r0[0], r0[1], r0[2], r0[3]);
                pC[slot] = make_int2(r0[4], r0[5]);
            } else {
                int r = j - NP;
                cinfo[slot - NP] = make_int2(rp[r], rp[r + 1]);
            }
        }
    }
}

// ---------- customer-side mean-agg (single segment) ----------
__device__ __forceinline__ void acc8(uint4 v, float* sum) {
    float t[8]; unpack8(v, t);
    #pragma unroll
    for (int k = 0; k < 8; ++k) sum[k] += t[k];
}
__device__ __forceinline__ void agg8se(int s, int e, const int* __restrict__ pm,
                                       const uint4* __restrict__ tgt,
                                       int lane, float* acc) {
    float sum[8] = {0, 0, 0, 0, 0, 0, 0, 0};
    int i = s;
    for (; i + 4 <= e; i += 4) {
        int d0 = pm[i], d1 = pm[i + 1], d2 = pm[i + 2], d3 = pm[i + 3];
        uint4 v0 = tgt[(size_t)d0 * 8 + lane];
        uint4 v1 = tgt[(size_t)d1 * 8 + lane];
        uint4 v2 = tgt[(size_t)d2 * 8 + lane];
        uint4 v3 = tgt[(size_t)d3 * 8 + lane];
        acc8(v0, sum); acc8(v1, sum); acc8(v2, sum); acc8(v3, sum);
    }
    for (; i < e; ++i) {
        uint4 v = tgt[(size_t)pm[i] * 8 + lane];
        acc8(v, sum);
    }
    int deg = e - s;
    float sc = 1.0f / (float)(deg > 1 ? deg : 1);
    #pragma unroll
    for (int k = 0; k < 8; ++k) acc[k] += sum[k] * sc;
}

// per-edge table/scale select for the merged product run
__device__ __forceinline__ const uint4* tblsel(int i, int b1, int b3, int b4,
                                               const uint4* c16, const uint4* p16,
                                               const uint4* g16, const uint4* b16) {
    const uint4* t = c16;
    if (i >= b1) t = p16;     // sim & cop both read p16
    if (i >= b3) t = g16;
    if (i >= b4) t = b16;
    return t;
}
__device__ __forceinline__ float sclsel(int i, int b1, int b2, int b3, int b4,
                                        float s0, float s1, float s2, float s3, float s4) {
    float s = s0;
    if (i >= b1) s = s1;
    if (i >= b2) s = s2;
    if (i >= b3) s = s3;
    if (i >= b4) s = s4;
    return s;
}
__device__ __forceinline__ void accw(uint4 v, float s, float* acc) {
    float t[8]; unpack8(v, t);
    #pragma unroll
    for (int k = 0; k < 8; ++k) acc[k] += t[k] * s;
}

// ---------- fused layer (degree-balanced rows, merged product runs) ----------
// modes 0/1: write next-snapshot only. mode 2: out = 0.25*(s0+s1+s2+acc).
__global__ void layer_kernel(
    const int* __restrict__ perm,
    const int4* __restrict__ pA, const int2* __restrict__ pC,
    const int2* __restrict__ cinfo,
    const int* __restrict__ pm,
    const uint4* __restrict__ c16, const uint4* __restrict__ p16,
    const uint4* __restrict__ g16, const uint4* __restrict__ b16,
    uint4* __restrict__ c16n, uint4* __restrict__ p16n,
    const float* __restrict__ cw, const float* __restrict__ pw,
    const uint4* __restrict__ s1c, const uint4* __restrict__ s1p,
    float* __restrict__ outc, float* __restrict__ outp,
    int mode)
{
    int t = blockIdx.x * blockDim.x + threadIdx.x;
    int gid = t >> 3;
    int lane = t & 7;
    float acc[8];
    if (gid < NP) {
        int row = perm[gid];                      // original product row
        size_t idx = (size_t)row * 8 + lane;
        int4 ia = pA[gid];
        int2 ic = pC[gid];
        int b0 = ia.x, b1 = ia.y, b2 = ia.z, b3 = ia.w, b4 = ic.x, b5 = ic.y;
        int d0g = b1 - b0, d1g = b2 - b1, d2g = b3 - b2, d3g = b4 - b3, d4g = b5 - b4;
        float s0 = 1.0f / (float)(d0g > 1 ? d0g : 1);
        float s1 = 0.5f / (float)(d1g > 1 ? d1g : 1);
        float s2 = 0.3f / (float)(d2g > 1 ? d2g : 1);
        float s3 = 0.2f / (float)(d3g > 1 ? d3g : 1);
        float s4 = 0.2f / (float)(d4g > 1 ? d4g : 1);
        float base[8]; unpack8(p16[idx], base);
        #pragma unroll
        for (int k = 0; k < 8; ++k) acc[k] = base[k];
        int i = b0;
        for (; i + 4 <= b5; i += 4) {
            int e0 = pm[i], e1 = pm[i + 1], e2 = pm[i + 2], e3 = pm[i + 3];
            const uint4* t0 = tblsel(i,     b1, b3, b4, c16, p16, g16, b16);
            const uint4* t1 = tblsel(i + 1, b1, b3, b4, c16, p16, g16, b16);
            const uint4* t2 = tblsel(i + 2, b1, b3, b4, c16, p16, g16, b16);
            const uint4* t3 = tblsel(i + 3, b1, b3, b4, c16, p16, g16, b16);
            float w0 = sclsel(i,     b1, b2, b3, b4, s0, s1, s2, s3, s4);
            float w1 = sclsel(i + 1, b1, b2, b3, b4, s0, s1, s2, s3, s4);
            float w2 = sclsel(i + 2, b1, b2, b3, b4, s0, s1, s2, s3, s4);
            float w3 = sclsel(i + 3, b1, b2, b3, b4, s0, s1, s2, s3, s4);
            uint4 v0 = t0[(size_t)e0 * 8 + lane];
            uint4 v1 = t1[(size_t)e1 * 8 + lane];
            uint4 v2 = t2[(size_t)e2 * 8 + lane];
            uint4 v3 = t3[(size_t)e3 * 8 + lane];
            accw(v0, w0, acc); accw(v1, w1, acc); accw(v2, w2, acc); accw(v3, w3, acc);
        }
        for (; i < b5; ++i) {
            int e0 = pm[i];
            const uint4* t0 = tblsel(i, b1, b3, b4, c16, p16, g16, b16);
            float w0 = sclsel(i, b1, b2, b3, b4, s0, s1, s2, s3, s4);
            uint4 v0 = t0[(size_t)e0 * 8 + lane];
            accw(v0, w0, acc);
        }
        if (mode != 2) {
            p16n[idx] = pack8(acc);
        } else {
            const f32x4* s0p = (const f32x4*)(pw + (size_t)row * 64 + lane * 8);
            f32x4 a0 = __builtin_nontemporal_load(s0p);
            f32x4 a1 = __builtin_nontemporal_load(s0p + 1);
            u32x4 s1v = __builtin_nontemporal_load((const u32x4*)&s1p[idx]);
            float sv[8]; unpack8v(s1v, sv);
            f32x4 o0, o1;
            o0.x = 0.25f * (a0.x + sv[0] + base[0] + acc[0]);
            o0.y = 0.25f * (a0.y + sv[1] + base[1] + acc[1]);
            o0.z = 0.25f * (a0.z + sv[2] + base[2] + acc[2]);
            o0.w = 0.25f * (a0.w + sv[3] + base[3] + acc[3]);
            o1.x = 0.25f * (a1.x + sv[4] + base[4] + acc[4]);
            o1.y = 0.25f * (a1.y + sv[5] + base[5] + acc[5]);
            o1.z = 0.25f * (a1.z + sv[6] + base[6] + acc[6]);
            o1.w = 0.25f * (a1.w + sv[7] + base[7] + acc[7]);
            f32x4* o = (f32x4*)(outp + (size_t)row * 64 + lane * 8);
            __builtin_nontemporal_store(o0, o);
            __builtin_nontemporal_store(o1, o + 1);
        }
    } else if (gid < ROWS) {
        int row = perm[gid] - NP;                 // original customer row
        size_t idx = (size_t)row * 8 + lane;
        int2 se = cinfo[gid - NP];
        #pragma unroll
        for (int k = 0; k < 8; ++k) acc[k] = 0.f;
        agg8se(se.x, se.y, pm, p16, lane, acc);
        if (mode != 2) {
            c16n[idx] = pack8(acc);
        } else {
            float base[8]; unpack8(c16[idx], base);                       // s2
            const f32x4* s0c = (const f32x4*)(cw + (size_t)row * 64 + lane * 8);
            f32x4 a0 = __builtin_nontemporal_load(s0c);
            f32x4 a1 = __builtin_nontemporal_load(s0c + 1);
            u32x4 s1v = __builtin_nontemporal_load((const u32x4*)&s1c[idx]);
            float sv[8]; unpack8v(s1v, sv);                               // s1
            f32x4 o0, o1;
            o0.x = 0.25f * (a0.x + sv[0] + base[0] + acc[0]);
            o0.y = 0.25f * (a0.y + sv[1] + base[1] + acc[1]);
            o0.z = 0.25f * (a0.z + sv[2] + base[2] + acc[2]);
            o0.w = 0.25f * (a0.w + sv[3] + base[3] + acc[3]);
            o1.x = 0.25f * (a1.x + sv[4] + base[4] + acc[4]);
            o1.y = 0.25f * (a1.y + sv[5] + base[5] + acc[5]);
            o1.z = 0.25f * (a1.z + sv[6] + base[6] + acc[6]);
            o1.w = 0.25f * (a1.w + sv[7] + base[7] + acc[7]);
            f32x4* o = (f32x4*)(outc + (size_t)row * 64 + lane * 8);
            __builtin_nontemporal_store(o0, o);
            __builtin_nontemporal_store(o1, o + 1);
        }
    }
}

extern "C" void kernel_launch(void* const* d_in, const int* in_sizes, int n_in,
                              void* d_out, int out_size, void* d_ws, size_t ws_size,
                              hipStream_t stream) {
    const float* cust_w  = (const float*)d_in[0];
    const float* prod_w  = (const float*)d_in[1];
    const float* group_w = (const float*)d_in[2];
    const float* brand_w = (const float*)d_in[3];

    const int n_purch = in_sizes[4];
    const int n_pby   = in_sizes[6];
    const int n_sim   = in_sizes[8];
    const int n_cop   = in_sizes[10];
    const int n_bel   = in_sizes[12];
    const int n_comp  = in_sizes[14];
    const int n_edges[6] = { n_purch, n_pby, n_sim, n_cop, n_bel, n_comp };

    const size_t CSZ = (size_t)NC * 64;
    const size_t PSZ = (size_t)NP * 64;

    // ---- workspace layout ----
    char* base = (char*)d_ws;
    uint4* c16A = (uint4*)base;                 base += (size_t)NC * 128;
    uint4* c16B = (uint4*)base;                 base += (size_t)NC * 128;
    uint4* p16A = (uint4*)base;                 base += (size_t)NP * 128;
    uint4* p16B = (uint4*)base;                 base += (size_t)NP * 128;
    uint4* g16  = (uint4*)base;                 base += (size_t)NG * 128;
    uint4* b16  = (uint4*)base;                 base += (size_t)NB * 128;

    int* rp_all = (int*)base;                   base += (size_t)RTOT * 4;
    long long tot_edges = 0;
    for (int k = 0; k < 6; ++k) tot_edges += n_edges[k];
    int* pm_all = (int*)base;                   base += tot_edges * 4;
    u32* stage  = (u32*)base;                   base += tot_edges * 4;
    const int NEDGE = cdiv(tot_edges, CH);
    int* bhist  = (int*)base;                   base += (size_t)NEDGE * NBKT * 4;
    int* gcount = (int*)base;                   base += (size_t)NBKT * 4;
    int* gbinc  = (int*)base;                   base += 256 * 4;         // adjacent to gcount: one memset
    int* gbase  = (int*)base;                   base += (size_t)(NBKT + 1) * 4;
    int* gcur   = (int*)base;                   base += (size_t)NBKT * 4;
    int* gcur256= (int*)base;                   base += 256 * 4;
    int* perm   = (int*)base;                   base += (size_t)ROWS * 4;
    int4* pA    = (int4*)base;                  base += (size_t)NP * 16;
    int2* pC    = (int2*)base;                  base += (size_t)NP * 8;
    int2* cinfo = (int2*)base;                  base += (size_t)NC * 8;

    float* out_c = (float*)d_out;
    float* out_p = out_c + CSZ;
    float* out_g = out_p + PSZ;
    float* out_b = out_g + (size_t)NG * 64;

    const int BT = 256;

    // ---- edge descriptor ----
    Edges6 E;
    E.src[0] = (const int*)d_in[4];  E.dst[0] = (const int*)d_in[5];
    E.src[1] = (const int*)d_in[6];  E.dst[1] = (const int*)d_in[7];
    E.src[2] = (const int*)d_in[8];  E.dst[2] = (const int*)d_in[9];
    E.src[3] = (const int*)d_in[10]; E.dst[3] = (const int*)d_in[11];
    E.src[4] = (const int*)d_in[12]; E.dst[4] = (const int*)d_in[13];
    E.src[5] = (const int*)d_in[14]; E.dst[5] = (const int*)d_in[15];
    E.cum[0] = 0;
    for (int k = 0; k < 6; ++k) E.cum[k + 1] = E.cum[k] + n_edges[k];
    const int TOT = E.cum[6];

    hipMemsetAsync(gcount, 0, ((size_t)NBKT + 256) * 4, stream);   // gcount + gbinc

    // ---- fused convert + bucket-count (overlapped in one launch) ----
    const long long CVT = (long long)(NC + NP + NG + NB) * 8;
    const int NCONV = cdiv(CVT, BT);
    conv_bcount<<<NCONV + NEDGE, BT, 0, stream>>>(
        cust_w, prod_w, group_w, brand_w, c16A, p16A, g16, b16, out_g, out_b,
        E, gcount, bhist, TOT, NCONV);

    bscan<<<1, SCAN_B, 0, stream>>>(gcount, gbase, gcur, NBKT);
    msplit<<<NEDGE, BT, 0, stream>>>(E, gcur, bhist, stage, TOT);
    sortb<<<NBKT, 512, 0, stream>>>(gbase, stage, pm_all, rp_all, RTOT);

    // ---- degree-balanced row permutation (permrp folded into rowplace) ----
    rowhist<<<cdiv(ROWS, RCH), 256, 0, stream>>>(rp_all, gbinc, ROWS);
    rowscan<<<1, 256, 0, stream>>>(gbinc, gcur256);
    rowplace<<<cdiv(ROWS, RCH), 256, 0, stream>>>(rp_all, gcur256, perm, pA, pC, cinfo, ROWS);

    // ---- 3 fused layers; d_out written only by layer 2 (deferred mean) ----
    const long long LTHREADS = (long long)ROWS * 8;
    layer_kernel<<<cdiv(LTHREADS, BT), BT, 0, stream>>>(
        perm, pA, pC, cinfo, pm_all,
        c16A, p16A, g16, b16, c16B, p16B,
        cust_w, prod_w, c16B, p16B, out_c, out_p, 0);
    layer_kernel<<<cdiv(LTHREADS, BT), BT, 0, stream>>>(
        perm, pA, pC, cinfo, pm_all,
        c16B, p16B, g16, b16, c16A, p16A,
        cust_w, prod_w, c16B, p16B, out_c, out_p, 1);
    layer_kernel<<<cdiv(LTHREADS, BT), BT, 0, stream>>>(
        perm, pA, pC, cinfo, pm_all,
        c16A, p16A, g16, b16, c16B, p16B,           // s2 = A (gather source)
        cust_w, prod_w, c16B, p16B,                 // s0 = inputs, s1 = B
        out_c, out_p, 2);
}